// Round 15
// baseline (643.660 us; speedup 1.0000x reference)
//
#include <hip/hip_runtime.h>
#include <hip/hip_bf16.h>

#define NN      50000
#define NE      800000
#define ETOT    850000
#define NG      256
#define HC      256
#define NBLK    ((NN + 255) / 256)   // 196

typedef __attribute__((ext_vector_type(8))) short bf8;
typedef __attribute__((ext_vector_type(4))) float f4;

__device__ inline float lrelu(float v) { return v > 0.f ? v : 0.2f * v; }

__device__ inline unsigned short f2bf(float f) {          // RNE f32->bf16
    unsigned int u = __float_as_uint(f);
    unsigned int r = (u + 0x7FFFu + ((u >> 16) & 1u)) >> 16;
    return (unsigned short)r;
}
__device__ inline float bf2f(unsigned short u) {
    return __uint_as_float((unsigned int)u << 16);
}

// ---- layer-0 GEMM (K=9): ONE WAVE PER NODE, lane owns 4 channels ----
__global__ __launch_bounds__(256, 8) void gemm_h_kernel(
    const float* __restrict__ x, const float* __restrict__ W,
    const float* __restrict__ asrc, const float* __restrict__ adst,
    unsigned short* __restrict__ h, float* __restrict__ alsrc,
    float* __restrict__ aldst) {
    int l = threadIdx.x & 63;
    int n = __builtin_amdgcn_readfirstlane(blockIdx.x * 4 + (threadIdx.x >> 6));
    int c0 = l * 4;
    float acc[4] = {0.f, 0.f, 0.f, 0.f};
#pragma unroll
    for (int k = 0; k < 9; ++k) {
        float xv = x[n * 9 + k];                   // n is SGPR -> s_load
        float4 wv = *(const float4*)(W + k * 256 + c0);
        acc[0] = fmaf(xv, wv.x, acc[0]);
        acc[1] = fmaf(xv, wv.y, acc[1]);
        acc[2] = fmaf(xv, wv.z, acc[2]);
        acc[3] = fmaf(xv, wv.w, acc[3]);
    }
    uint2 pk;
    pk.x = (unsigned int)f2bf(acc[0]) | ((unsigned int)f2bf(acc[1]) << 16);
    pk.y = (unsigned int)f2bf(acc[2]) | ((unsigned int)f2bf(acc[3]) << 16);
    *(uint2*)(h + (size_t)n * 256 + c0) = pk;
    int hd = l >> 4;
    int ci = (l & 15) * 4;
    float ps = 0.f, pd = 0.f;
#pragma unroll
    for (int i = 0; i < 4; ++i) {
        ps = fmaf(acc[i], asrc[hd * 64 + ci + i], ps);
        pd = fmaf(acc[i], adst[hd * 64 + ci + i], pd);
    }
#pragma unroll
    for (int o = 1; o < 16; o <<= 1) {
        ps += __shfl_xor(ps, o, 64);
        pd += __shfl_xor(pd, o, 64);
    }
    if ((l & 15) == 0) {
        alsrc[n * 4 + hd] = ps;
        aldst[n * 4 + hd] = pd;
    }
}

// ---- W transpose + bf16 convert, both layers: Wt[l][c][k] = bf16(W[l][k][c]) ----
__global__ void wt_kernel(const float* __restrict__ W, unsigned short* __restrict__ Wt) {
    int b = blockIdx.x;                  // 0..511: layer = b>>8, c = b&255
    int lay = b >> 8, c = b & 255, k = threadIdx.x;
    Wt[(size_t)lay * 65536 + c * 256 + k] = f2bf(W[(size_t)lay * 65536 + k * 256 + c]);
}

// ---- layers 1,2 GEMM via MFMA bf16. Block: 64x256 tile, 4 waves of 64x64. ----
#define HS_STRIDE 258
__global__ __launch_bounds__(256) void gemm_mfma_kernel(
    const unsigned short* __restrict__ X, const unsigned short* __restrict__ Wt,
    const float* __restrict__ asrc, const float* __restrict__ adst,
    unsigned short* __restrict__ h, float* __restrict__ alsrc, float* __restrict__ aldst) {
    __shared__ unsigned short hs[64 * HS_STRIDE];
    int tid = threadIdx.x;
    int w = tid >> 6, l = tid & 63;
    int m0 = blockIdx.x * 64;
    int wc = w * 64;
    int lr = l & 15, lk = l >> 4;

    f4 acc[4][4];
#pragma unroll
    for (int mi = 0; mi < 4; ++mi)
#pragma unroll
        for (int ni = 0; ni < 4; ++ni) acc[mi][ni] = (f4)(0.f);

    const unsigned short* arow[4];
#pragma unroll
    for (int mi = 0; mi < 4; ++mi) {
        int row = m0 + mi * 16 + lr;
        if (row >= NN) row = NN - 1;
        arow[mi] = X + (size_t)row * 256 + lk * 8;
    }
    const unsigned short* brow[4];
#pragma unroll
    for (int ni = 0; ni < 4; ++ni)
        brow[ni] = Wt + (size_t)(wc + ni * 16 + lr) * 256 + lk * 8;

#pragma unroll
    for (int kk = 0; kk < 8; ++kk) {
        bf8 a[4], b[4];
#pragma unroll
        for (int mi = 0; mi < 4; ++mi) a[mi] = *(const bf8*)(arow[mi] + kk * 32);
#pragma unroll
        for (int ni = 0; ni < 4; ++ni) b[ni] = *(const bf8*)(brow[ni] + kk * 32);
#pragma unroll
        for (int mi = 0; mi < 4; ++mi)
#pragma unroll
            for (int ni = 0; ni < 4; ++ni)
                acc[mi][ni] = __builtin_amdgcn_mfma_f32_16x16x32_bf16(
                    a[mi], b[ni], acc[mi][ni], 0, 0, 0);
    }

    // ---- attention-logit epilogue: wave w owns head w for the 64 rows ----
    int hd = w;
    float aSv[4], aDv[4];
#pragma unroll
    for (int ni = 0; ni < 4; ++ni) {
        aSv[ni] = asrc[hd * 64 + ni * 16 + lr];
        aDv[ni] = adst[hd * 64 + ni * 16 + lr];
    }
#pragma unroll
    for (int mi = 0; mi < 4; ++mi) {
#pragma unroll
        for (int r = 0; r < 4; ++r) {
            float ps = 0.f, pd = 0.f;
#pragma unroll
            for (int ni = 0; ni < 4; ++ni) {
                ps = fmaf(acc[mi][ni][r], aSv[ni], ps);
                pd = fmaf(acc[mi][ni][r], aDv[ni], pd);
            }
#pragma unroll
            for (int o = 1; o < 16; o <<= 1) {
                ps += __shfl_xor(ps, o, 64);
                pd += __shfl_xor(pd, o, 64);
            }
            if (lr == 0) {
                int row = m0 + mi * 16 + 4 * lk + r;
                if (row < NN) {
                    alsrc[row * 4 + hd] = ps;
                    aldst[row * 4 + hd] = pd;
                }
            }
        }
    }

    // ---- h store: regs -> LDS (bf16) -> coalesced global ----
#pragma unroll
    for (int mi = 0; mi < 4; ++mi)
#pragma unroll
        for (int ni = 0; ni < 4; ++ni) {
            int C = wc + ni * 16 + lr;
#pragma unroll
            for (int r = 0; r < 4; ++r) {
                int R = mi * 16 + 4 * lk + r;
                hs[R * HS_STRIDE + C] = f2bf(acc[mi][ni][r]);
            }
        }
    __syncthreads();
    {
        int row = tid & 63, q = tid >> 6;          // wave q copies quarter q
        int grow = m0 + row;
        if (grow < NN) {
            const unsigned short* src = hs + row * HS_STRIDE + q * 64;
            unsigned short* dst = h + (size_t)grow * 256 + q * 64;
#pragma unroll
            for (int i = 0; i < 16; ++i)
                *(uint2*)(dst + i * 4) = *(const uint2*)(src + i * 4);
        }
    }
}

// ---- CSR build ----
__global__ void hist_kernel(const int* __restrict__ ei, int* __restrict__ deg) {
    int t = blockIdx.x * 256 + threadIdx.x;
    if (t >= ETOT) return;
    int d = (t < NE) ? ei[NE + t] : t - NE;
    atomicAdd(&deg[d], 1);
}

__global__ void scan1_kernel(const int* __restrict__ deg, int* __restrict__ bsum) {
    __shared__ int red[256];
    int b = blockIdx.x, t = threadIdx.x;
    int idx = b * 256 + t;
    red[t] = (idx < NN) ? deg[idx] : 0;
    __syncthreads();
    for (int s = 128; s > 0; s >>= 1) { if (t < s) red[t] += red[t + s]; __syncthreads(); }
    if (t == 0) bsum[b] = red[0];
}

__global__ void scan2_kernel(const int* __restrict__ bsum, int* __restrict__ boff,
                             int* __restrict__ rowptr) {
    __shared__ int s[256];
    int t = threadIdx.x;
    int v = (t < NBLK) ? bsum[t] : 0;
    s[t] = v;
    __syncthreads();
    for (int d = 1; d < 256; d <<= 1) {
        int x = s[t];
        int a = (t >= d) ? s[t - d] : 0;
        __syncthreads();
        s[t] = x + a;
        __syncthreads();
    }
    if (t < NBLK) boff[t] = s[t] - v;
    if (t == NBLK - 1) rowptr[NN] = s[t];
}

__global__ void scan3_kernel(const int* __restrict__ deg, const int* __restrict__ boff,
                             int* __restrict__ rowptr, int* __restrict__ cursor) {
    __shared__ int s[256];
    int b = blockIdx.x, t = threadIdx.x;
    int idx = b * 256 + t;
    int v = (idx < NN) ? deg[idx] : 0;
    s[t] = v;
    __syncthreads();
    for (int d = 1; d < 256; d <<= 1) {
        int x = s[t];
        int a = (t >= d) ? s[t - d] : 0;
        __syncthreads();
        s[t] = x + a;
        __syncthreads();
    }
    if (idx < NN) {
        int r = boff[b] + s[t] - v;
        rowptr[idx] = r;
        cursor[idx] = r;
    }
}

__global__ void scatter_kernel(const int* __restrict__ ei, int* __restrict__ cursor,
                               int* __restrict__ esrc) {
    int t = blockIdx.x * 256 + threadIdx.x;
    if (t >= ETOT) return;
    int s, d;
    if (t < NE) { s = ei[t]; d = ei[NE + t]; } else { s = d = t - NE; }
    int pos = atomicAdd(&cursor[d], 1);
    esrc[pos] = s;
}

// ---- graph boundaries from sorted batch ----
__global__ void gbound_kernel(const int* __restrict__ batch, int* __restrict__ gstart) {
    int n = blockIdx.x * 256 + threadIdx.x;
    if (n >= NN) return;
    int b = batch[n];
    int prev = (n == 0) ? -1 : batch[n - 1];
    for (int g = prev + 1; g <= b; ++g) gstart[g] = n;
    if (n == NN - 1)
        for (int g = b + 1; g <= NG; ++g) gstart[g] = NN;
}

// ---- fused per-dst aggregation: ONE WAVE PER NODE, 16-edge phases.
// Weight phase: lane i computes exp-weight for edge eb+(i>>2), head i&3
// (1 esrc load + 1 alsrc gather + 1 exp per phase, vs 16 redundant each).
// Accumulate: wj via bpermute-shfl, sj via uniform shfl (readlane -> SGPR
// h base) so the 16 h-row loads issue back-to-back, register-dependent only.
// Block 0 additionally zeroes S/S2 (512 floats) for bn_stats. ----
__global__ __launch_bounds__(256, 8) void agg_csr_kernel(
    const int* __restrict__ rowptr, const int* __restrict__ esrc,
    const float* __restrict__ alsrc, const float* __restrict__ aldst,
    const unsigned short* __restrict__ h, const float* __restrict__ bias,
    unsigned short* __restrict__ out, float* __restrict__ S) {
    if (blockIdx.x == 0 && threadIdx.x < 128)
        ((float4*)S)[threadIdx.x] = make_float4(0.f, 0.f, 0.f, 0.f);
    int l = threadIdx.x & 63;
    int n = blockIdx.x * 4 + (threadIdx.x >> 6);   // NN % 4 == 0
    int hd = l >> 4;
    int q = l >> 2;                                // edge slot 0..15
    float adw = aldst[n * 4 + (l & 3)];
    float4 bv = *(const float4*)(bias + l * 4);
    int beg = rowptr[n], end = rowptr[n + 1];
    float a0 = 0.f, a1 = 0.f, a2 = 0.f, a3 = 0.f, den = 0.f;
    for (int eb = beg; eb < end; eb += 16) {
        int cnt = min(16, end - eb);
        int sw = 0;
        float w = 0.f;
        if (q < cnt) {
            sw = esrc[eb + q];
            w = __expf(lrelu(alsrc[sw * 4 + (l & 3)] + adw));
        }
#pragma unroll 4
        for (int j = 0; j < cnt; ++j) {
            float wj = __shfl(w, j * 4 + hd, 64);
            int sj = __shfl(sw, j * 4, 64);        // uniform src -> readlane
            uint2 hv = *(const uint2*)(h + (size_t)sj * 256 + l * 4);
            den += wj;
            a0 = fmaf(wj, bf2f((unsigned short)hv.x), a0);
            a1 = fmaf(wj, bf2f((unsigned short)(hv.x >> 16)), a1);
            a2 = fmaf(wj, bf2f((unsigned short)hv.y), a2);
            a3 = fmaf(wj, bf2f((unsigned short)(hv.y >> 16)), a3);
        }
    }
    float r = 1.f / (den + 1e-16f);
    float v0 = fmaf(a0, r, bv.x), v1 = fmaf(a1, r, bv.y);
    float v2 = fmaf(a2, r, bv.z), v3 = fmaf(a3, r, bv.w);
    uint2 pk;
    pk.x = (unsigned int)f2bf(v0) | ((unsigned int)f2bf(v1) << 16);
    pk.y = (unsigned int)f2bf(v2) | ((unsigned int)f2bf(v3) << 16);
    *(uint2*)(out + (size_t)n * 256 + l * 4) = pk;
}

// ---- fused BN stats (bf16 input; S/S2 pre-zeroed by agg block 0) ----
__global__ void bn_stats_kernel(const unsigned short* __restrict__ x1b,
                                float* __restrict__ S, float* __restrict__ S2) {
    int j = threadIdx.x, b = blockIdx.x;
    float s = 0.f, s2 = 0.f;
    for (int n = b; n < NN; n += gridDim.x) {
        float v = bf2f(x1b[(size_t)n * 256 + j]);
        s += v;
        s2 = fmaf(v, v, s2);
    }
    atomicAdd(&S[j], s);
    atomicAdd(&S2[j], s2);
}

// ---- BN apply + relu -> xnext(bf16); per-node softmax stats m[n], rs[n]=1/sum. ----
__global__ __launch_bounds__(256, 8) void bn_apply_kernel(
    const unsigned short* __restrict__ x1b, const float* __restrict__ S,
    const float* __restrict__ S2, const float* __restrict__ gamma,
    const float* __restrict__ beta, unsigned short* __restrict__ xnext,
    float* __restrict__ mrow, float* __restrict__ rsrow) {
    int l = threadIdx.x & 63;
    int n = __builtin_amdgcn_readfirstlane(blockIdx.x * 4 + (threadIdx.x >> 6));
    int c = l * 4;
    uint2 xp = *(const uint2*)(x1b + (size_t)n * 256 + c);
    float4 s4 = *(const float4*)(S + c);
    float4 q4 = *(const float4*)(S2 + c);
    float4 g4 = *(const float4*)(gamma + c);
    float4 b4 = *(const float4*)(beta + c);
    float v[4];
    {
        float xs[4] = {bf2f((unsigned short)xp.x), bf2f((unsigned short)(xp.x >> 16)),
                       bf2f((unsigned short)xp.y), bf2f((unsigned short)(xp.y >> 16))};
        float ss[4] = {s4.x, s4.y, s4.z, s4.w};
        float qs[4] = {q4.x, q4.y, q4.z, q4.w};
        float gs[4] = {g4.x, g4.y, g4.z, g4.w};
        float bs[4] = {b4.x, b4.y, b4.z, b4.w};
#pragma unroll
        for (int i = 0; i < 4; ++i) {
            float mu = ss[i] * (1.f / NN);
            float var = fmaxf(qs[i] * (1.f / NN) - mu * mu, 0.f);
            v[i] = fmaxf((xs[i] - mu) * rsqrtf(var + 1e-5f) * gs[i] + bs[i], 0.f);
        }
    }
    float m = fmaxf(fmaxf(v[0], v[1]), fmaxf(v[2], v[3]));
#pragma unroll
    for (int o = 1; o < 64; o <<= 1) m = fmaxf(m, __shfl_xor(m, o, 64));
    float e0 = __expf(v[0] - m), e1 = __expf(v[1] - m);
    float e2 = __expf(v[2] - m), e3 = __expf(v[3] - m);
    float sum = e0 + e1 + e2 + e3;
#pragma unroll
    for (int o = 1; o < 64; o <<= 1) sum += __shfl_xor(sum, o, 64);
    uint2 pk;
    pk.x = (unsigned int)f2bf(v[0]) | ((unsigned int)f2bf(v[1]) << 16);
    pk.y = (unsigned int)f2bf(v[2]) | ((unsigned int)f2bf(v[3]) << 16);
    *(uint2*)(xnext + (size_t)n * 256 + c) = pk;
    if (l == 0) { mrow[n] = m; rsrow[n] = 1.f / sum; }
}

// ---- graph pooling: block = (graph g, node-chunk), reads xnext bf16 ----
__global__ __launch_bounds__(256) void pool_kernel(
    const unsigned short* __restrict__ xnext,
    const float* __restrict__ mrow, const float* __restrict__ rsrow,
    const int* __restrict__ gstart, float* __restrict__ f) {
    int g = blockIdx.x;
    int chunk = blockIdx.y;                        // 0..3
    int j = threadIdx.x;
    int beg = gstart[g], end = gstart[g + 1];
    int per = (end - beg + 3) >> 2;
    int nb = beg + chunk * per;
    int ne = min(nb + per, end);
    if (nb >= ne) return;
    float acc = 0.f;
#pragma unroll 4
    for (int n = nb; n < ne; ++n) {
        float v = bf2f(xnext[(size_t)n * 256 + j]);
        acc += __expf(v - mrow[n]) * rsrow[n];
    }
    atomicAdd(&f[g * 256 + j], acc);
}

__global__ void mlp_kernel(const float* __restrict__ A, const float* __restrict__ W,
                           const float* __restrict__ b, float* __restrict__ out, int do_relu) {
    int i = blockIdx.x, j = threadIdx.x;
    __shared__ float row[256];
    row[j] = A[i * 256 + j];
    __syncthreads();
    float acc = b[j];
#pragma unroll 8
    for (int k = 0; k < 256; ++k) acc = fmaf(row[k], W[k * 256 + j], acc);
    if (do_relu) acc = fmaxf(acc, 0.f);
    out[i * 256 + j] = acc;
}

extern "C" void kernel_launch(void* const* d_in, const int* in_sizes, int n_in,
                              void* d_out, int out_size, void* d_ws, size_t ws_size,
                              hipStream_t stream) {
    const float* x0     = (const float*)d_in[0];
    const int*   ei     = (const int*)d_in[1];
    const int*   batch  = (const int*)d_in[2];
    const float* W0     = (const float*)d_in[3];
    const float* asrc0  = (const float*)d_in[4];
    const float* adst0  = (const float*)d_in[5];
    const float* bias0  = (const float*)d_in[6];
    const float* W12    = (const float*)d_in[7];
    const float* asrc12 = (const float*)d_in[8];
    const float* adst12 = (const float*)d_in[9];
    const float* bias12 = (const float*)d_in[10];
    const float* gamma  = (const float*)d_in[11];
    const float* beta   = (const float*)d_in[12];
    const float* Wm1    = (const float*)d_in[13];
    const float* bm1    = (const float*)d_in[14];
    const float* Wm2    = (const float*)d_in[15];
    const float* bm2    = (const float*)d_in[16];
    float* out = (float*)d_out;

    const size_t NODE_F = (size_t)NN * 256;
    unsigned short* h16  = (unsigned short*)d_ws;               // NODE_F ushorts
    unsigned short* x1b  = h16 + NODE_F;                        // NODE_F ushorts
    unsigned short* xb16 = x1b + NODE_F;                        // NODE_F ushorts
    unsigned short* wt   = xb16 + NODE_F;                       // 2*65536 ushorts
    float* alsrc  = (float*)(wt + 2 * 65536);
    float* aldst  = alsrc + (size_t)NN * 4;
    float* S      = aldst + (size_t)NN * 4;
    float* S2     = S + 256;
    float* fpool  = S2 + 256;
    float* g_buf  = fpool + 65536;
    float* mrow   = g_buf + 65536;
    float* rsrow  = mrow + NN;
    int*   deg    = (int*)(rsrow + NN);
    int*   rowptr = deg + NN + 1;
    int*   cursor = rowptr + NN + 1;
    int*   bsum   = cursor + NN + 1;
    int*   boff   = bsum + NBLK + 1;
    int*   gstart = boff + NBLK + 1;
    int*   esrc   = gstart + NG + 1;

    // CSR by dst (shared by all layers)
    hipMemsetAsync(deg, 0, (NN + 1) * sizeof(int), stream);
    hist_kernel<<<(ETOT + 255) / 256, 256, 0, stream>>>(ei, deg);
    scan1_kernel<<<NBLK, 256, 0, stream>>>(deg, bsum);
    scan2_kernel<<<1, 256, 0, stream>>>(bsum, boff, rowptr);
    scan3_kernel<<<NBLK, 256, 0, stream>>>(deg, boff, rowptr, cursor);
    scatter_kernel<<<(ETOT + 255) / 256, 256, 0, stream>>>(ei, cursor, esrc);

    // graph boundaries (batch is sorted)
    gbound_kernel<<<(NN + 255) / 256, 256, 0, stream>>>(batch, gstart);

    // bf16-transposed weights for layers 1,2 (one launch)
    wt_kernel<<<512, 256, 0, stream>>>(W12, wt);

    hipMemsetAsync(fpool, 0, 65536 * sizeof(float), stream);

    for (int l = 0; l < 3; ++l) {
        const float* as = (l == 0) ? asrc0 : asrc12 + (size_t)(l - 1) * 256;
        const float* ad = (l == 0) ? adst0 : adst12 + (size_t)(l - 1) * 256;
        const float* bs = (l == 0) ? bias0 : bias12 + (size_t)(l - 1) * 256;

        if (l == 0) {
            gemm_h_kernel<<<NN / 4, 256, 0, stream>>>(
                x0, W0, as, ad, h16, alsrc, aldst);
        } else {
            gemm_mfma_kernel<<<(NN + 63) / 64, 256, 0, stream>>>(
                xb16, wt + (size_t)(l - 1) * 65536, as, ad, h16, alsrc, aldst);
        }

        // agg also zeroes S/S2 (block 0) for the following bn_stats
        agg_csr_kernel<<<NN / 4, 256, 0, stream>>>(rowptr, esrc, alsrc, aldst, h16, bs, x1b, S);

        bn_stats_kernel<<<1024, 256, 0, stream>>>(x1b, S, S2);

        bn_apply_kernel<<<NN / 4, 256, 0, stream>>>(
            x1b, S, S2, gamma + l * 256, beta + l * 256, xb16, mrow, rsrow);

        pool_kernel<<<dim3(NG, 4), 256, 0, stream>>>(
            xb16, mrow, rsrow, gstart, fpool);
    }

    mlp_kernel<<<256, 256, 0, stream>>>(fpool, Wm1, bm1, g_buf, 1);
    mlp_kernel<<<256, 256, 0, stream>>>(g_buf, Wm2, bm2, out, 0);
}

// Round 16
// 617.967 us; speedup vs baseline: 1.0416x; 1.0416x over previous
//
#include <hip/hip_runtime.h>
#include <hip/hip_bf16.h>

#define NN      50000
#define NE      800000
#define ETOT    850000
#define NG      256
#define HC      256
#define NBLK    ((NN + 255) / 256)   // 196

typedef __attribute__((ext_vector_type(8))) short bf8;
typedef __attribute__((ext_vector_type(4))) float f4;

__device__ inline float lrelu(float v) { return v > 0.f ? v : 0.2f * v; }

__device__ inline unsigned short f2bf(float f) {          // RNE f32->bf16
    unsigned int u = __float_as_uint(f);
    unsigned int r = (u + 0x7FFFu + ((u >> 16) & 1u)) >> 16;
    return (unsigned short)r;
}
__device__ inline float bf2f(unsigned short u) {
    return __uint_as_float((unsigned int)u << 16);
}

// ---- layer-0 GEMM (K=9): ONE WAVE PER NODE, lane owns 4 channels ----
__global__ __launch_bounds__(256, 8) void gemm_h_kernel(
    const float* __restrict__ x, const float* __restrict__ W,
    const float* __restrict__ asrc, const float* __restrict__ adst,
    unsigned short* __restrict__ h, float* __restrict__ alsrc,
    float* __restrict__ aldst) {
    int l = threadIdx.x & 63;
    int n = __builtin_amdgcn_readfirstlane(blockIdx.x * 4 + (threadIdx.x >> 6));
    int c0 = l * 4;
    float acc[4] = {0.f, 0.f, 0.f, 0.f};
#pragma unroll
    for (int k = 0; k < 9; ++k) {
        float xv = x[n * 9 + k];                   // n is SGPR -> s_load
        float4 wv = *(const float4*)(W + k * 256 + c0);
        acc[0] = fmaf(xv, wv.x, acc[0]);
        acc[1] = fmaf(xv, wv.y, acc[1]);
        acc[2] = fmaf(xv, wv.z, acc[2]);
        acc[3] = fmaf(xv, wv.w, acc[3]);
    }
    uint2 pk;
    pk.x = (unsigned int)f2bf(acc[0]) | ((unsigned int)f2bf(acc[1]) << 16);
    pk.y = (unsigned int)f2bf(acc[2]) | ((unsigned int)f2bf(acc[3]) << 16);
    *(uint2*)(h + (size_t)n * 256 + c0) = pk;
    int hd = l >> 4;
    int ci = (l & 15) * 4;
    float ps = 0.f, pd = 0.f;
#pragma unroll
    for (int i = 0; i < 4; ++i) {
        ps = fmaf(acc[i], asrc[hd * 64 + ci + i], ps);
        pd = fmaf(acc[i], adst[hd * 64 + ci + i], pd);
    }
#pragma unroll
    for (int o = 1; o < 16; o <<= 1) {
        ps += __shfl_xor(ps, o, 64);
        pd += __shfl_xor(pd, o, 64);
    }
    if ((l & 15) == 0) {
        alsrc[n * 4 + hd] = ps;
        aldst[n * 4 + hd] = pd;
    }
}

// ---- W transpose + bf16 convert, both layers: Wt[l][c][k] = bf16(W[l][k][c]) ----
__global__ void wt_kernel(const float* __restrict__ W, unsigned short* __restrict__ Wt) {
    int b = blockIdx.x;                  // 0..511: layer = b>>8, c = b&255
    int lay = b >> 8, c = b & 255, k = threadIdx.x;
    Wt[(size_t)lay * 65536 + c * 256 + k] = f2bf(W[(size_t)lay * 65536 + k * 256 + c]);
}

// ---- layers 1,2 GEMM via MFMA bf16. Block: 64x256 tile, 4 waves of 64x64. ----
#define HS_STRIDE 258
__global__ __launch_bounds__(256) void gemm_mfma_kernel(
    const unsigned short* __restrict__ X, const unsigned short* __restrict__ Wt,
    const float* __restrict__ asrc, const float* __restrict__ adst,
    unsigned short* __restrict__ h, float* __restrict__ alsrc, float* __restrict__ aldst) {
    __shared__ unsigned short hs[64 * HS_STRIDE];
    int tid = threadIdx.x;
    int w = tid >> 6, l = tid & 63;
    int m0 = blockIdx.x * 64;
    int wc = w * 64;
    int lr = l & 15, lk = l >> 4;

    f4 acc[4][4];
#pragma unroll
    for (int mi = 0; mi < 4; ++mi)
#pragma unroll
        for (int ni = 0; ni < 4; ++ni) acc[mi][ni] = (f4)(0.f);

    const unsigned short* arow[4];
#pragma unroll
    for (int mi = 0; mi < 4; ++mi) {
        int row = m0 + mi * 16 + lr;
        if (row >= NN) row = NN - 1;
        arow[mi] = X + (size_t)row * 256 + lk * 8;
    }
    const unsigned short* brow[4];
#pragma unroll
    for (int ni = 0; ni < 4; ++ni)
        brow[ni] = Wt + (size_t)(wc + ni * 16 + lr) * 256 + lk * 8;

#pragma unroll
    for (int kk = 0; kk < 8; ++kk) {
        bf8 a[4], b[4];
#pragma unroll
        for (int mi = 0; mi < 4; ++mi) a[mi] = *(const bf8*)(arow[mi] + kk * 32);
#pragma unroll
        for (int ni = 0; ni < 4; ++ni) b[ni] = *(const bf8*)(brow[ni] + kk * 32);
#pragma unroll
        for (int mi = 0; mi < 4; ++mi)
#pragma unroll
            for (int ni = 0; ni < 4; ++ni)
                acc[mi][ni] = __builtin_amdgcn_mfma_f32_16x16x32_bf16(
                    a[mi], b[ni], acc[mi][ni], 0, 0, 0);
    }

    // ---- attention-logit epilogue: wave w owns head w for the 64 rows ----
    int hd = w;
    float aSv[4], aDv[4];
#pragma unroll
    for (int ni = 0; ni < 4; ++ni) {
        aSv[ni] = asrc[hd * 64 + ni * 16 + lr];
        aDv[ni] = adst[hd * 64 + ni * 16 + lr];
    }
#pragma unroll
    for (int mi = 0; mi < 4; ++mi) {
#pragma unroll
        for (int r = 0; r < 4; ++r) {
            float ps = 0.f, pd = 0.f;
#pragma unroll
            for (int ni = 0; ni < 4; ++ni) {
                ps = fmaf(acc[mi][ni][r], aSv[ni], ps);
                pd = fmaf(acc[mi][ni][r], aDv[ni], pd);
            }
#pragma unroll
            for (int o = 1; o < 16; o <<= 1) {
                ps += __shfl_xor(ps, o, 64);
                pd += __shfl_xor(pd, o, 64);
            }
            if (lr == 0) {
                int row = m0 + mi * 16 + 4 * lk + r;
                if (row < NN) {
                    alsrc[row * 4 + hd] = ps;
                    aldst[row * 4 + hd] = pd;
                }
            }
        }
    }

    // ---- h store: regs -> LDS (bf16) -> coalesced global ----
#pragma unroll
    for (int mi = 0; mi < 4; ++mi)
#pragma unroll
        for (int ni = 0; ni < 4; ++ni) {
            int C = wc + ni * 16 + lr;
#pragma unroll
            for (int r = 0; r < 4; ++r) {
                int R = mi * 16 + 4 * lk + r;
                hs[R * HS_STRIDE + C] = f2bf(acc[mi][ni][r]);
            }
        }
    __syncthreads();
    {
        int row = tid & 63, q = tid >> 6;          // wave q copies quarter q
        int grow = m0 + row;
        if (grow < NN) {
            const unsigned short* src = hs + row * HS_STRIDE + q * 64;
            unsigned short* dst = h + (size_t)grow * 256 + q * 64;
#pragma unroll
            for (int i = 0; i < 16; ++i)
                *(uint2*)(dst + i * 4) = *(const uint2*)(src + i * 4);
        }
    }
}

// ---- CSR build ----
__global__ void hist_kernel(const int* __restrict__ ei, int* __restrict__ deg) {
    int t = blockIdx.x * 256 + threadIdx.x;
    if (t >= ETOT) return;
    int d = (t < NE) ? ei[NE + t] : t - NE;
    atomicAdd(&deg[d], 1);
}

__global__ void scan1_kernel(const int* __restrict__ deg, int* __restrict__ bsum) {
    __shared__ int red[256];
    int b = blockIdx.x, t = threadIdx.x;
    int idx = b * 256 + t;
    red[t] = (idx < NN) ? deg[idx] : 0;
    __syncthreads();
    for (int s = 128; s > 0; s >>= 1) { if (t < s) red[t] += red[t + s]; __syncthreads(); }
    if (t == 0) bsum[b] = red[0];
}

__global__ void scan2_kernel(const int* __restrict__ bsum, int* __restrict__ boff,
                             int* __restrict__ rowptr) {
    __shared__ int s[256];
    int t = threadIdx.x;
    int v = (t < NBLK) ? bsum[t] : 0;
    s[t] = v;
    __syncthreads();
    for (int d = 1; d < 256; d <<= 1) {
        int x = s[t];
        int a = (t >= d) ? s[t - d] : 0;
        __syncthreads();
        s[t] = x + a;
        __syncthreads();
    }
    if (t < NBLK) boff[t] = s[t] - v;
    if (t == NBLK - 1) rowptr[NN] = s[t];
}

__global__ void scan3_kernel(const int* __restrict__ deg, const int* __restrict__ boff,
                             int* __restrict__ rowptr, int* __restrict__ cursor) {
    __shared__ int s[256];
    int b = blockIdx.x, t = threadIdx.x;
    int idx = b * 256 + t;
    int v = (idx < NN) ? deg[idx] : 0;
    s[t] = v;
    __syncthreads();
    for (int d = 1; d < 256; d <<= 1) {
        int x = s[t];
        int a = (t >= d) ? s[t - d] : 0;
        __syncthreads();
        s[t] = x + a;
        __syncthreads();
    }
    if (idx < NN) {
        int r = boff[b] + s[t] - v;
        rowptr[idx] = r;
        cursor[idx] = r;
    }
}

__global__ void scatter_kernel(const int* __restrict__ ei, int* __restrict__ cursor,
                               int* __restrict__ esrc) {
    int t = blockIdx.x * 256 + threadIdx.x;
    if (t >= ETOT) return;
    int s, d;
    if (t < NE) { s = ei[t]; d = ei[NE + t]; } else { s = d = t - NE; }
    int pos = atomicAdd(&cursor[d], 1);
    esrc[pos] = s;
}

// ---- graph boundaries from sorted batch ----
__global__ void gbound_kernel(const int* __restrict__ batch, int* __restrict__ gstart) {
    int n = blockIdx.x * 256 + threadIdx.x;
    if (n >= NN) return;
    int b = batch[n];
    int prev = (n == 0) ? -1 : batch[n - 1];
    for (int g = prev + 1; g <= b; ++g) gstart[g] = n;
    if (n == NN - 1)
        for (int g = b + 1; g <= NG; ++g) gstart[g] = NN;
}

// ---- fused per-dst aggregation: ONE WAVE PER NODE (r14 plain body — two
// restructures of this loop regressed; plain per-lane form pipelines best).
// Block 0 additionally zeroes S/S2 (512 floats) for bn_stats. ----
__global__ __launch_bounds__(256, 8) void agg_csr_kernel(
    const int* __restrict__ rowptr, const int* __restrict__ esrc,
    const float* __restrict__ alsrc, const float* __restrict__ aldst,
    const unsigned short* __restrict__ h, const float* __restrict__ bias,
    unsigned short* __restrict__ out, float* __restrict__ S) {
    if (blockIdx.x == 0 && threadIdx.x < 128)
        ((float4*)S)[threadIdx.x] = make_float4(0.f, 0.f, 0.f, 0.f);
    int l = threadIdx.x & 63;
    int n = blockIdx.x * 4 + (threadIdx.x >> 6);   // NN % 4 == 0
    int hd = l >> 4;
    float ad = aldst[n * 4 + hd];
    float4 bv = *(const float4*)(bias + l * 4);
    int beg = rowptr[n], end = rowptr[n + 1];
    float a0 = 0.f, a1 = 0.f, a2 = 0.f, a3 = 0.f, den = 0.f;
#pragma unroll 4
    for (int e = beg; e < end; ++e) {
        int s = esrc[e];
        float wgt = __expf(lrelu(alsrc[s * 4 + hd] + ad));
        uint2 hv = *(const uint2*)(h + (size_t)s * 256 + l * 4);
        den += wgt;
        a0 = fmaf(wgt, bf2f((unsigned short)hv.x), a0);
        a1 = fmaf(wgt, bf2f((unsigned short)(hv.x >> 16)), a1);
        a2 = fmaf(wgt, bf2f((unsigned short)hv.y), a2);
        a3 = fmaf(wgt, bf2f((unsigned short)(hv.y >> 16)), a3);
    }
    float r = 1.f / (den + 1e-16f);
    float v0 = fmaf(a0, r, bv.x), v1 = fmaf(a1, r, bv.y);
    float v2 = fmaf(a2, r, bv.z), v3 = fmaf(a3, r, bv.w);
    uint2 pk;
    pk.x = (unsigned int)f2bf(v0) | ((unsigned int)f2bf(v1) << 16);
    pk.y = (unsigned int)f2bf(v2) | ((unsigned int)f2bf(v3) << 16);
    *(uint2*)(out + (size_t)n * 256 + l * 4) = pk;
}

// ---- fused BN stats (bf16 input; S/S2 pre-zeroed by agg block 0) ----
__global__ void bn_stats_kernel(const unsigned short* __restrict__ x1b,
                                float* __restrict__ S, float* __restrict__ S2) {
    int j = threadIdx.x, b = blockIdx.x;
    float s = 0.f, s2 = 0.f;
    for (int n = b; n < NN; n += gridDim.x) {
        float v = bf2f(x1b[(size_t)n * 256 + j]);
        s += v;
        s2 = fmaf(v, v, s2);
    }
    atomicAdd(&S[j], s);
    atomicAdd(&S2[j], s2);
}

// ---- BN apply + relu -> xnext(bf16); per-node softmax stats m[n], rs[n]=1/sum. ----
__global__ __launch_bounds__(256, 8) void bn_apply_kernel(
    const unsigned short* __restrict__ x1b, const float* __restrict__ S,
    const float* __restrict__ S2, const float* __restrict__ gamma,
    const float* __restrict__ beta, unsigned short* __restrict__ xnext,
    float* __restrict__ mrow, float* __restrict__ rsrow) {
    int l = threadIdx.x & 63;
    int n = __builtin_amdgcn_readfirstlane(blockIdx.x * 4 + (threadIdx.x >> 6));
    int c = l * 4;
    uint2 xp = *(const uint2*)(x1b + (size_t)n * 256 + c);
    float4 s4 = *(const float4*)(S + c);
    float4 q4 = *(const float4*)(S2 + c);
    float4 g4 = *(const float4*)(gamma + c);
    float4 b4 = *(const float4*)(beta + c);
    float v[4];
    {
        float xs[4] = {bf2f((unsigned short)xp.x), bf2f((unsigned short)(xp.x >> 16)),
                       bf2f((unsigned short)xp.y), bf2f((unsigned short)(xp.y >> 16))};
        float ss[4] = {s4.x, s4.y, s4.z, s4.w};
        float qs[4] = {q4.x, q4.y, q4.z, q4.w};
        float gs[4] = {g4.x, g4.y, g4.z, g4.w};
        float bs[4] = {b4.x, b4.y, b4.z, b4.w};
#pragma unroll
        for (int i = 0; i < 4; ++i) {
            float mu = ss[i] * (1.f / NN);
            float var = fmaxf(qs[i] * (1.f / NN) - mu * mu, 0.f);
            v[i] = fmaxf((xs[i] - mu) * rsqrtf(var + 1e-5f) * gs[i] + bs[i], 0.f);
        }
    }
    float m = fmaxf(fmaxf(v[0], v[1]), fmaxf(v[2], v[3]));
#pragma unroll
    for (int o = 1; o < 64; o <<= 1) m = fmaxf(m, __shfl_xor(m, o, 64));
    float e0 = __expf(v[0] - m), e1 = __expf(v[1] - m);
    float e2 = __expf(v[2] - m), e3 = __expf(v[3] - m);
    float sum = e0 + e1 + e2 + e3;
#pragma unroll
    for (int o = 1; o < 64; o <<= 1) sum += __shfl_xor(sum, o, 64);
    uint2 pk;
    pk.x = (unsigned int)f2bf(v[0]) | ((unsigned int)f2bf(v[1]) << 16);
    pk.y = (unsigned int)f2bf(v[2]) | ((unsigned int)f2bf(v[3]) << 16);
    *(uint2*)(xnext + (size_t)n * 256 + c) = pk;
    if (l == 0) { mrow[n] = m; rsrow[n] = 1.f / sum; }
}

// ---- graph pooling: block = (graph g, node-chunk), reads xnext bf16 ----
__global__ __launch_bounds__(256) void pool_kernel(
    const unsigned short* __restrict__ xnext,
    const float* __restrict__ mrow, const float* __restrict__ rsrow,
    const int* __restrict__ gstart, float* __restrict__ f) {
    int g = blockIdx.x;
    int chunk = blockIdx.y;                        // 0..3
    int j = threadIdx.x;
    int beg = gstart[g], end = gstart[g + 1];
    int per = (end - beg + 3) >> 2;
    int nb = beg + chunk * per;
    int ne = min(nb + per, end);
    if (nb >= ne) return;
    float acc = 0.f;
#pragma unroll 4
    for (int n = nb; n < ne; ++n) {
        float v = bf2f(xnext[(size_t)n * 256 + j]);
        acc += __expf(v - mrow[n]) * rsrow[n];
    }
    atomicAdd(&f[g * 256 + j], acc);
}

__global__ void mlp_kernel(const float* __restrict__ A, const float* __restrict__ W,
                           const float* __restrict__ b, float* __restrict__ out, int do_relu) {
    int i = blockIdx.x, j = threadIdx.x;
    __shared__ float row[256];
    row[j] = A[i * 256 + j];
    __syncthreads();
    float acc = b[j];
#pragma unroll 8
    for (int k = 0; k < 256; ++k) acc = fmaf(row[k], W[k * 256 + j], acc);
    if (do_relu) acc = fmaxf(acc, 0.f);
    out[i * 256 + j] = acc;
}

extern "C" void kernel_launch(void* const* d_in, const int* in_sizes, int n_in,
                              void* d_out, int out_size, void* d_ws, size_t ws_size,
                              hipStream_t stream) {
    const float* x0     = (const float*)d_in[0];
    const int*   ei     = (const int*)d_in[1];
    const int*   batch  = (const int*)d_in[2];
    const float* W0     = (const float*)d_in[3];
    const float* asrc0  = (const float*)d_in[4];
    const float* adst0  = (const float*)d_in[5];
    const float* bias0  = (const float*)d_in[6];
    const float* W12    = (const float*)d_in[7];
    const float* asrc12 = (const float*)d_in[8];
    const float* adst12 = (const float*)d_in[9];
    const float* bias12 = (const float*)d_in[10];
    const float* gamma  = (const float*)d_in[11];
    const float* beta   = (const float*)d_in[12];
    const float* Wm1    = (const float*)d_in[13];
    const float* bm1    = (const float*)d_in[14];
    const float* Wm2    = (const float*)d_in[15];
    const float* bm2    = (const float*)d_in[16];
    float* out = (float*)d_out;

    const size_t NODE_F = (size_t)NN * 256;
    unsigned short* h16  = (unsigned short*)d_ws;               // NODE_F ushorts
    unsigned short* x1b  = h16 + NODE_F;                        // NODE_F ushorts
    unsigned short* xb16 = x1b + NODE_F;                        // NODE_F ushorts
    unsigned short* wt   = xb16 + NODE_F;                       // 2*65536 ushorts
    float* alsrc  = (float*)(wt + 2 * 65536);
    float* aldst  = alsrc + (size_t)NN * 4;
    float* S      = aldst + (size_t)NN * 4;
    float* S2     = S + 256;
    float* fpool  = S2 + 256;
    float* g_buf  = fpool + 65536;
    float* mrow   = g_buf + 65536;
    float* rsrow  = mrow + NN;
    int*   deg    = (int*)(rsrow + NN);
    int*   rowptr = deg + NN + 1;
    int*   cursor = rowptr + NN + 1;
    int*   bsum   = cursor + NN + 1;
    int*   boff   = bsum + NBLK + 1;
    int*   gstart = boff + NBLK + 1;
    int*   esrc   = gstart + NG + 1;

    // CSR by dst (shared by all layers)
    hipMemsetAsync(deg, 0, (NN + 1) * sizeof(int), stream);
    hist_kernel<<<(ETOT + 255) / 256, 256, 0, stream>>>(ei, deg);
    scan1_kernel<<<NBLK, 256, 0, stream>>>(deg, bsum);
    scan2_kernel<<<1, 256, 0, stream>>>(bsum, boff, rowptr);
    scan3_kernel<<<NBLK, 256, 0, stream>>>(deg, boff, rowptr, cursor);
    scatter_kernel<<<(ETOT + 255) / 256, 256, 0, stream>>>(ei, cursor, esrc);

    // graph boundaries (batch is sorted)
    gbound_kernel<<<(NN + 255) / 256, 256, 0, stream>>>(batch, gstart);

    // bf16-transposed weights for layers 1,2 (one launch)
    wt_kernel<<<512, 256, 0, stream>>>(W12, wt);

    hipMemsetAsync(fpool, 0, 65536 * sizeof(float), stream);

    for (int l = 0; l < 3; ++l) {
        const float* as = (l == 0) ? asrc0 : asrc12 + (size_t)(l - 1) * 256;
        const float* ad = (l == 0) ? adst0 : adst12 + (size_t)(l - 1) * 256;
        const float* bs = (l == 0) ? bias0 : bias12 + (size_t)(l - 1) * 256;

        if (l == 0) {
            gemm_h_kernel<<<NN / 4, 256, 0, stream>>>(
                x0, W0, as, ad, h16, alsrc, aldst);
        } else {
            gemm_mfma_kernel<<<(NN + 63) / 64, 256, 0, stream>>>(
                xb16, wt + (size_t)(l - 1) * 65536, as, ad, h16, alsrc, aldst);
        }

        // agg also zeroes S/S2 (block 0) for the following bn_stats
        agg_csr_kernel<<<NN / 4, 256, 0, stream>>>(rowptr, esrc, alsrc, aldst, h16, bs, x1b, S);

        bn_stats_kernel<<<1024, 256, 0, stream>>>(x1b, S, S2);

        bn_apply_kernel<<<NN / 4, 256, 0, stream>>>(
            x1b, S, S2, gamma + l * 256, beta + l * 256, xb16, mrow, rsrow);

        pool_kernel<<<dim3(NG, 4), 256, 0, stream>>>(
            xb16, mrow, rsrow, gstart, fpool);
    }

    mlp_kernel<<<256, 256, 0, stream>>>(fpool, Wm1, bm1, g_buf, 1);
    mlp_kernel<<<256, 256, 0, stream>>>(g_buf, Wm2, bm2, out, 0);
}